// Round 4
// baseline (299.830 us; speedup 1.0000x reference)
//
#include <hip/hip_runtime.h>
#include <stdint.h>

typedef _Float16 half_t;
typedef __attribute__((ext_vector_type(8))) _Float16 f16x8;
typedef __attribute__((ext_vector_type(4))) _Float16 f16x4;
typedef __attribute__((ext_vector_type(4))) float f32x4;

#define SQN 4096
#define SKN 16448
#define NROPE 16384
#define NSPLIT 12
#define NTILES 514          // 16448 / 32
#define SCQ 0.090168441360f // log2(e) / 16  (folded into Q at proj time)

// ---------------- weight transpose: W[k][n] f32 -> WT[n][k] f16 (4 mats) ------
__global__ __launch_bounds__(256) void wt_kernel(const float* __restrict__ qw,
    const float* __restrict__ kw, const float* __restrict__ vw, const float* __restrict__ ow,
    half_t* __restrict__ wt)
{
    __shared__ float tile[64][65];
    int b = blockIdx.x;
    int mat = b >> 4, t4 = b & 15;
    int k0 = (t4 >> 2) << 6, n0 = (t4 & 3) << 6;
    const float* W = (mat == 0) ? qw : (mat == 1) ? kw : (mat == 2) ? vw : ow;
    half_t* WT = wt + mat * 65536;
    int t = threadIdx.x;
#pragma unroll
    for (int j = 0; j < 16; ++j) {
        int e = j * 256 + t;
        tile[e >> 6][e & 63] = W[(k0 + (e >> 6)) * 256 + n0 + (e & 63)];
    }
    __syncthreads();
#pragma unroll
    for (int j = 0; j < 16; ++j) {
        int e = j * 256 + t;
        WT[(n0 + (e >> 6)) * 256 + k0 + (e & 63)] = (half_t)tile[e & 63][e >> 6];
    }
}

// ---------------- fused QKV projection + bias + RoPE (no LDS, W from L2) -----
// grid: 64 (Q) + 257 (K) + 257 (V) = 578 blocks, 256 threads (4 waves x 16 rows)
__global__ __launch_bounds__(256) void proj_kernel(
    const float* __restrict__ query, const float* __restrict__ key, const float* __restrict__ value,
    const float* __restrict__ cosp, const float* __restrict__ sinp,
    const half_t* __restrict__ wt,
    const float* __restrict__ qb, const float* __restrict__ kb, const float* __restrict__ vb,
    half_t* __restrict__ Qe, half_t* __restrict__ Ke, half_t* __restrict__ VT)
{
    int b = blockIdx.x;
    int mode; long row0;
    const float* X; const half_t* W; const float* bias;
    if (b < 64)       { mode = 0; row0 = (long)b * 64;         X = query; W = wt;           bias = qb; }
    else if (b < 321) { mode = 1; row0 = (long)(b - 64) * 64;  X = key;   W = wt + 65536;   bias = kb; }
    else              { mode = 2; row0 = (long)(b - 321) * 64; X = value; W = wt + 131072;  bias = vb; }

    int tid = threadIdx.x;
    int w = tid >> 6, l = tid & 63;
    int l16 = l & 15, l4 = l >> 4;
    long rw0 = row0 + w * 16;

    f32x4 acc[16];
#pragma unroll
    for (int i = 0; i < 16; ++i) acc[i] = (f32x4){0.f, 0.f, 0.f, 0.f};

    const float* xrow = X + (rw0 + l16) * 256;
    for (int ks = 0; ks < 8; ++ks) {
        f32x4 xa = *reinterpret_cast<const f32x4*>(xrow + ks * 32 + l4 * 8);
        f32x4 xb = *reinterpret_cast<const f32x4*>(xrow + ks * 32 + l4 * 8 + 4);
        f16x8 af;
#pragma unroll
        for (int j = 0; j < 4; ++j) { af[j] = (half_t)xa[j]; af[4 + j] = (half_t)xb[j]; }
#pragma unroll
        for (int nt = 0; nt < 16; ++nt) {
            f16x8 bf = *reinterpret_cast<const f16x8*>(W + (nt * 16 + l16) * 256 + ks * 32 + l4 * 8);
            acc[nt] = __builtin_amdgcn_mfma_f32_16x16x32_f16(af, bf, acc[nt], 0, 0, 0);
        }
    }

    bool dorope = (mode == 0) || (mode == 1 && row0 < NROPE);
#pragma unroll
    for (int nt = 0; nt < 16; ++nt) {
        int d = nt * 16 + l16;
        float bv = bias[d];
        f32x4 v = acc[nt];
#pragma unroll
        for (int r = 0; r < 4; ++r) v[r] += bv;
        if (dorope) {
#pragma unroll
            for (int r = 0; r < 4; ++r) {
                long m = rw0 + l4 * 4 + r;
                long crow = (mode == 0) ? m : (m >> 2);
                float c = cosp[crow * 256 + d];
                float s = sinp[crow * 256 + d];
                float val = v[r];
                float other = __shfl_xor(val, 1);
                float rot = (d & 1) ? other : -other;
                v[r] = val * c + rot * s;
                if (mode == 0) v[r] *= SCQ;     // fold softmax scale into Q
            }
        }
        if (mode == 2) {        // V stored transposed: VT[d][kv]
            f16x4 pk;
#pragma unroll
            for (int r = 0; r < 4; ++r) pk[r] = (half_t)v[r];
            *reinterpret_cast<f16x4*>(VT + (long)d * SKN + rw0 + l4 * 4) = pk;
        } else {
            half_t* O = (mode == 0) ? Qe : Ke;
#pragma unroll
            for (int r = 0; r < 4; ++r)
                O[(rw0 + l4 * 4 + r) * 256 + d] = (half_t)v[r];
        }
    }
}

// ---------------- flash attention with KV-split + reg-prefetch ---------------
// grid: 64 q-blocks x 12 kv-chunks = 768 blocks, 256 threads (4 waves x 16 q rows)
// 4-wave blocks: unified VGPR+AGPR ~160/wave caps CU at 12 waves; 8-wave blocks
// couldn't pack 2/CU (R3: occupancy 22%). 4-wave blocks pack 3/CU.
__global__ __launch_bounds__(256) void flash_kernel(
    const half_t* __restrict__ Qe, const half_t* __restrict__ Ke, const half_t* __restrict__ VT,
    half_t* __restrict__ AOp, float* __restrict__ Lse)
{
    __shared__ __align__(16) half_t Ks[32 * 264];   // [kv][d 256, pad 264]  16.9 KB
    __shared__ __align__(16) half_t Vs[256 * 40];   // [d][kv 32, pad 40]    20.5 KB
    __shared__ __align__(16) half_t Ps[4][16 * 40]; // per-wave P             5.1 KB

    int b = blockIdx.x;
    int qb = b & 63;
    int chunk = b >> 6;
    int tid = threadIdx.x;
    int w = tid >> 6, l = tid & 63;
    int l16 = l & 15, l4 = l >> 4;
    long qw0 = (long)qb * 64 + w * 16;

    int t0 = (NTILES * chunk) / NSPLIT;
    int t1 = (NTILES * (chunk + 1)) / NSPLIT;

    f16x8 qf[8];    // Q (pre-scaled by SCQ) as B-operand
#pragma unroll
    for (int ks = 0; ks < 8; ++ks)
        qf[ks] = *reinterpret_cast<const f16x8*>(Qe + (qw0 + l16) * 256 + ks * 32 + l4 * 8);

    f32x4 o[16];
#pragma unroll
    for (int i = 0; i < 16; ++i) o[i] = (f32x4){0.f, 0.f, 0.f, 0.f};
    float mrun = -3.0e38f;
    float lsum = 0.0f;

    // staging (256 threads): K row=tid>>3, 64B contiguous at col (tid&7)*32;
    //                        V d=tid, the 32-kv row (64B)
    const int krow = tid >> 3, kcol = (tid & 7) * 32;
    const int vd = tid;
    f16x8* dK = reinterpret_cast<f16x8*>(Ks + krow * 264 + kcol);
    f16x8* dV = reinterpret_cast<f16x8*>(Vs + vd * 40);
    f16x8 kr[4], vr[4];
    {
        long kv0 = (long)t0 * 32;
        const f16x8* sK = reinterpret_cast<const f16x8*>(Ke + (kv0 + krow) * 256 + kcol);
        const f16x8* sV = reinterpret_cast<const f16x8*>(VT + (long)vd * SKN + kv0);
#pragma unroll
        for (int j = 0; j < 4; ++j) { kr[j] = sK[j]; vr[j] = sV[j]; }
    }
#pragma unroll
    for (int j = 0; j < 4; ++j) { dK[j] = kr[j]; dV[j] = vr[j]; }
    __syncthreads();

    half_t* Pw = Ps[w];

    for (int t = t0; t < t1; ++t) {
        if (t + 1 < t1) {   // issue next-tile loads early (hide latency under compute)
            long kv0 = (long)(t + 1) * 32;
            const f16x8* sK = reinterpret_cast<const f16x8*>(Ke + (kv0 + krow) * 256 + kcol);
            const f16x8* sV = reinterpret_cast<const f16x8*>(VT + (long)vd * SKN + kv0);
#pragma unroll
            for (int j = 0; j < 4; ++j) { kr[j] = sK[j]; vr[j] = sV[j]; }
        }

        // swapped QK^T: S^T[kv][q]; lane: col=q=l16, row=kv
        f32x4 s0 = (f32x4){0.f, 0.f, 0.f, 0.f};
        f32x4 s1 = (f32x4){0.f, 0.f, 0.f, 0.f};
#pragma unroll
        for (int ks = 0; ks < 8; ++ks) {
            f16x8 ka0 = *reinterpret_cast<const f16x8*>(Ks + l16 * 264 + ks * 32 + l4 * 8);
            f16x8 ka1 = *reinterpret_cast<const f16x8*>(Ks + (16 + l16) * 264 + ks * 32 + l4 * 8);
            s0 = __builtin_amdgcn_mfma_f32_16x16x32_f16(ka0, qf[ks], s0, 0, 0, 0);
            s1 = __builtin_amdgcn_mfma_f32_16x16x32_f16(ka1, qf[ks], s1, 0, 0, 0);
        }

        float tv[8];
#pragma unroll
        for (int r = 0; r < 4; ++r) { tv[r] = s0[r]; tv[4 + r] = s1[r]; }
        float pm = tv[0];
#pragma unroll
        for (int i = 1; i < 8; ++i) pm = fmaxf(pm, tv[i]);
        pm = fmaxf(pm, __shfl_xor(pm, 16));
        pm = fmaxf(pm, __shfl_xor(pm, 32));

        if (!__all(pm - mrun <= 8.0f)) {    // defer-max rescale
            float mn = fmaxf(mrun, pm);
            float alpha = __builtin_amdgcn_exp2f(mrun - mn);
            lsum *= alpha;
            float ao[4];
#pragma unroll
            for (int r = 0; r < 4; ++r) ao[r] = __shfl(alpha, l4 * 4 + r);
#pragma unroll
            for (int i = 0; i < 16; ++i)
#pragma unroll
                for (int r = 0; r < 4; ++r) o[i][r] *= ao[r];
            mrun = mn;
        }

        float p[8];
        float psum = 0.f;
#pragma unroll
        for (int i = 0; i < 8; ++i) { p[i] = __builtin_amdgcn_exp2f(tv[i] - mrun); psum += p[i]; }
        psum += __shfl_xor(psum, 16);
        psum += __shfl_xor(psum, 32);
        lsum += psum;

        f16x4 pk0, pk1;
#pragma unroll
        for (int r = 0; r < 4; ++r) { pk0[r] = (half_t)p[r]; pk1[r] = (half_t)p[4 + r]; }
        *reinterpret_cast<f16x4*>(Pw + l16 * 40 + l4 * 4) = pk0;
        *reinterpret_cast<f16x4*>(Pw + l16 * 40 + 16 + l4 * 4) = pk1;

        // PV: A = P[q][kv32] (one b128), B = V[kv][d] from Vs
        f16x8 pa = *reinterpret_cast<const f16x8*>(Pw + l16 * 40 + l4 * 8);
#pragma unroll
        for (int nt = 0; nt < 16; ++nt) {
            f16x8 vbf = *reinterpret_cast<const f16x8*>(Vs + (nt * 16 + l16) * 40 + l4 * 8);
            o[nt] = __builtin_amdgcn_mfma_f32_16x16x32_f16(pa, vbf, o[nt], 0, 0, 0);
        }

        __syncthreads();                    // all waves done reading tile t
        if (t + 1 < t1) {
#pragma unroll
            for (int j = 0; j < 4; ++j) { dK[j] = kr[j]; dV[j] = vr[j]; }
        }
        __syncthreads();                    // tile t+1 visible
    }

    // epilogue: normalized f16 partials + LSE (amdgcn_logf = v_log_f32 = log2)
    float inv[4];
#pragma unroll
    for (int r = 0; r < 4; ++r) inv[r] = 1.0f / __shfl(lsum, l4 * 4 + r);
    half_t* Ab = AOp + ((long)chunk * SQN + qw0) * 256;
#pragma unroll
    for (int nt = 0; nt < 16; ++nt)
#pragma unroll
        for (int r = 0; r < 4; ++r)
            Ab[(l4 * 4 + r) * 256 + nt * 16 + l16] = (half_t)(o[nt][r] * inv[r]);
    if (l < 16)
        Lse[(long)chunk * SQN + qw0 + l16] = mrun + __builtin_amdgcn_logf(lsum);
}

// ---------------- combine KV-split partials -> AO (f16) ----------------------
__global__ __launch_bounds__(256) void reduce_kernel(
    const half_t* __restrict__ AOp, const float* __restrict__ Lse, half_t* __restrict__ AO)
{
    int tid = threadIdx.x;
    long q = (long)blockIdx.x * 4 + (tid >> 6);
    int d0 = (tid & 63) * 4;
    float ls[NSPLIT];
    float lmax = -3.0e38f;
#pragma unroll
    for (int i = 0; i < NSPLIT; ++i) { ls[i] = Lse[(long)i * SQN + q]; lmax = fmaxf(lmax, ls[i]); }
    f32x4 acc = (f32x4){0.f, 0.f, 0.f, 0.f};
    float wsum = 0.f;
#pragma unroll
    for (int i = 0; i < NSPLIT; ++i) {
        float wgt = __builtin_amdgcn_exp2f(ls[i] - lmax);
        wsum += wgt;
        f16x4 ov = *reinterpret_cast<const f16x4*>(AOp + ((long)i * SQN + q) * 256 + d0);
#pragma unroll
        for (int r = 0; r < 4; ++r) acc[r] += wgt * (float)ov[r];
    }
    float inv = 1.0f / wsum;
    f16x4 pk;
#pragma unroll
    for (int r = 0; r < 4; ++r) pk[r] = (half_t)(acc[r] * inv);
    *reinterpret_cast<f16x4*>(AO + q * 256 + d0) = pk;
}

// ---------------- O projection ----------------------------------------------
__global__ __launch_bounds__(256) void oproj_kernel(
    const half_t* __restrict__ AO, const half_t* __restrict__ WTo,
    const float* __restrict__ ob, float* __restrict__ out)
{
    int b = blockIdx.x;
    int tid = threadIdx.x;
    int w = tid >> 6, l = tid & 63;
    int l16 = l & 15, l4 = l >> 4;
    long r0 = (long)b * 64 + w * 16;
    f32x4 acc[16];
#pragma unroll
    for (int i = 0; i < 16; ++i) acc[i] = (f32x4){0.f, 0.f, 0.f, 0.f};
#pragma unroll
    for (int ks = 0; ks < 8; ++ks) {
        f16x8 af = *reinterpret_cast<const f16x8*>(AO + (r0 + l16) * 256 + ks * 32 + l4 * 8);
#pragma unroll
        for (int nt = 0; nt < 16; ++nt) {
            f16x8 bf = *reinterpret_cast<const f16x8*>(WTo + (nt * 16 + l16) * 256 + ks * 32 + l4 * 8);
            acc[nt] = __builtin_amdgcn_mfma_f32_16x16x32_f16(af, bf, acc[nt], 0, 0, 0);
        }
    }
#pragma unroll
    for (int nt = 0; nt < 16; ++nt) {
        int d = nt * 16 + l16;
        float bv = ob[d];
#pragma unroll
        for (int r = 0; r < 4; ++r)
            out[(r0 + l4 * 4 + r) * 256 + d] = acc[nt][r] + bv;
    }
}

extern "C" void kernel_launch(void* const* d_in, const int* in_sizes, int n_in,
                              void* d_out, int out_size, void* d_ws, size_t ws_size,
                              hipStream_t stream) {
    const float* query = (const float*)d_in[0];
    const float* key   = (const float*)d_in[1];
    const float* value = (const float*)d_in[2];
    const float* cosp  = (const float*)d_in[3];
    const float* sinp  = (const float*)d_in[4];
    const float* qw = (const float*)d_in[5];
    const float* qb = (const float*)d_in[6];
    const float* kw = (const float*)d_in[7];
    const float* kb = (const float*)d_in[8];
    const float* vw = (const float*)d_in[9];
    const float* vb = (const float*)d_in[10];
    const float* ow = (const float*)d_in[11];
    const float* ob = (const float*)d_in[12];

    char* ws = (char*)d_ws;
    half_t* Qe  = (half_t*)(ws);                     // 4096*256*2       = 2,097,152
    half_t* Ke  = (half_t*)(ws + 2097152);           // 16448*256*2      = 8,421,376
    half_t* VT  = (half_t*)(ws + 10518528);          // 256*16448*2      = 8,421,376
    half_t* WT  = (half_t*)(ws + 18939904);          // 4*256*256*2      = 524,288
    half_t* AOp = (half_t*)(ws + 19464192);          // 12*4096*256*2    = 25,165,824
    float*  Lse = (float*)(ws + 44630016);           // 12*4096*4        = 196,608
    half_t* AO  = (half_t*)(ws + 44826624);          // 4096*256*2       = 2,097,152
    // total ws use: 46,923,776 bytes (< 55,377,920 proven)

    hipLaunchKernelGGL(wt_kernel, dim3(64), dim3(256), 0, stream, qw, kw, vw, ow, WT);
    hipLaunchKernelGGL(proj_kernel, dim3(578), dim3(256), 0, stream,
                       query, key, value, cosp, sinp, WT, qb, kb, vb, Qe, Ke, VT);
    hipLaunchKernelGGL(flash_kernel, dim3(64 * NSPLIT), dim3(256), 0, stream, Qe, Ke, VT, AOp, Lse);
    hipLaunchKernelGGL(reduce_kernel, dim3(1024), dim3(256), 0, stream, AOp, Lse, AO);
    hipLaunchKernelGGL(oproj_kernel, dim3(64), dim3(256), 0, stream, AO, WT + 3 * 65536, ob, (float*)d_out);
}

// Round 5
// 205.316 us; speedup vs baseline: 1.4603x; 1.4603x over previous
//
#include <hip/hip_runtime.h>
#include <stdint.h>

typedef _Float16 half_t;
typedef __attribute__((ext_vector_type(8))) _Float16 f16x8;
typedef __attribute__((ext_vector_type(4))) _Float16 f16x4;
typedef __attribute__((ext_vector_type(4))) float f32x4;

#define SQN 4096
#define SKN 16448
#define NROPE 16384
#define NSPLIT 12
#define NTILES 514          // 16448 / 32
#define SCQ 0.090168441360f // log2(e) / 16  (folded into Q at proj time)

// async global->LDS, 16B per lane; LDS dest = wave-uniform base + lane*16
#define GLD16(gp, lp) __builtin_amdgcn_global_load_lds( \
    (const __attribute__((address_space(1))) void*)(const void*)(gp), \
    (__attribute__((address_space(3))) void*)(void*)(lp), 16, 0, 0)

// ---------------- weight transpose: W[k][n] f32 -> WT[n][k] f16 (4 mats) ------
__global__ __launch_bounds__(256) void wt_kernel(const float* __restrict__ qw,
    const float* __restrict__ kw, const float* __restrict__ vw, const float* __restrict__ ow,
    half_t* __restrict__ wt)
{
    __shared__ float tile[64][65];
    int b = blockIdx.x;
    int mat = b >> 4, t4 = b & 15;
    int k0 = (t4 >> 2) << 6, n0 = (t4 & 3) << 6;
    const float* W = (mat == 0) ? qw : (mat == 1) ? kw : (mat == 2) ? vw : ow;
    half_t* WT = wt + mat * 65536;
    int t = threadIdx.x;
#pragma unroll
    for (int j = 0; j < 16; ++j) {
        int e = j * 256 + t;
        tile[e >> 6][e & 63] = W[(k0 + (e >> 6)) * 256 + n0 + (e & 63)];
    }
    __syncthreads();
#pragma unroll
    for (int j = 0; j < 16; ++j) {
        int e = j * 256 + t;
        WT[(n0 + (e >> 6)) * 256 + k0 + (e & 63)] = (half_t)tile[e & 63][e >> 6];
    }
}

// ---------------- fused QKV projection + bias + RoPE -------------------------
// grid: 64 (Q) + 257 (K) + 257 (V) = 578 blocks, 256 threads (4 waves x 16 rows)
// Epilogue: Q/K via LDS transpose -> coalesced f16x8 stores; V direct to tiled
// VTb[tile][256 d][32 kv] layout (flash stages V as one contiguous 16KB DMA).
__global__ __launch_bounds__(256) void proj_kernel(
    const float* __restrict__ query, const float* __restrict__ key, const float* __restrict__ value,
    const float* __restrict__ cosp, const float* __restrict__ sinp,
    const half_t* __restrict__ wt,
    const float* __restrict__ qb, const float* __restrict__ kb, const float* __restrict__ vb,
    half_t* __restrict__ Qe, half_t* __restrict__ Ke, half_t* __restrict__ VTb)
{
    __shared__ __align__(16) half_t S[64 * 264];    // [row][d pad 264] for Q/K path

    int b = blockIdx.x;
    int mode; long row0;
    const float* X; const half_t* W; const float* bias;
    if (b < 64)       { mode = 0; row0 = (long)b * 64;         X = query; W = wt;           bias = qb; }
    else if (b < 321) { mode = 1; row0 = (long)(b - 64) * 64;  X = key;   W = wt + 65536;   bias = kb; }
    else              { mode = 2; row0 = (long)(b - 321) * 64; X = value; W = wt + 131072;  bias = vb; }

    int tid = threadIdx.x;
    int w = tid >> 6, l = tid & 63;
    int l16 = l & 15, l4 = l >> 4;
    long rw0 = row0 + w * 16;

    f32x4 acc[16];
#pragma unroll
    for (int i = 0; i < 16; ++i) acc[i] = (f32x4){0.f, 0.f, 0.f, 0.f};

    const float* xrow = X + (rw0 + l16) * 256;
    for (int ks = 0; ks < 8; ++ks) {
        f32x4 xa = *reinterpret_cast<const f32x4*>(xrow + ks * 32 + l4 * 8);
        f32x4 xb = *reinterpret_cast<const f32x4*>(xrow + ks * 32 + l4 * 8 + 4);
        f16x8 af;
#pragma unroll
        for (int j = 0; j < 4; ++j) { af[j] = (half_t)xa[j]; af[4 + j] = (half_t)xb[j]; }
#pragma unroll
        for (int nt = 0; nt < 16; ++nt) {
            f16x8 bf = *reinterpret_cast<const f16x8*>(W + (nt * 16 + l16) * 256 + ks * 32 + l4 * 8);
            acc[nt] = __builtin_amdgcn_mfma_f32_16x16x32_f16(af, bf, acc[nt], 0, 0, 0);
        }
    }

    bool dorope = (mode == 0) || (mode == 1 && row0 < NROPE);
#pragma unroll
    for (int nt = 0; nt < 16; ++nt) {
        int d = nt * 16 + l16;
        float bv = bias[d];
        f32x4 v = acc[nt];
#pragma unroll
        for (int r = 0; r < 4; ++r) v[r] += bv;
        if (dorope) {
#pragma unroll
            for (int r = 0; r < 4; ++r) {
                long m = rw0 + l4 * 4 + r;
                long crow = (mode == 0) ? m : (m >> 2);
                float c = cosp[crow * 256 + d];
                float s = sinp[crow * 256 + d];
                float val = v[r];
                float other = __shfl_xor(val, 1);
                float rot = (d & 1) ? other : -other;
                v[r] = val * c + rot * s;
                if (mode == 0) v[r] *= SCQ;     // fold softmax scale into Q
            }
        }
        if (mode == 2) {        // direct tiled store: VTb[kvb][d][kv&31]
            long kv = rw0 + l4 * 4;
            long kvb = kv >> 5;
            int  kvw = (int)(kv & 31);
            f16x4 pk;
#pragma unroll
            for (int r = 0; r < 4; ++r) pk[r] = (half_t)v[r];
            *reinterpret_cast<f16x4*>(VTb + kvb * 8192 + (long)d * 32 + kvw) = pk;
        } else {                // stage to LDS for coalesced row-major store
            int wrow = w * 16 + l4 * 4;
#pragma unroll
            for (int r = 0; r < 4; ++r)
                S[(wrow + r) * 264 + d] = (half_t)v[r];
        }
    }

    if (mode != 2) {
        __syncthreads();
        half_t* O = ((mode == 0) ? Qe : Ke) + row0 * 256;
#pragma unroll
        for (int i = 0; i < 8; ++i) {
            int e = (i * 256 + tid) * 8;        // 64 rows x 256 d, 16B chunks
            int row = e >> 8, col = e & 255;
            f16x8 val = *reinterpret_cast<const f16x8*>(&S[row * 264 + col]);
            *reinterpret_cast<f16x8*>(O + e) = val;
        }
    }
}

// ---------------- flash attention: DMA-staged, 4-wave blocks -----------------
// grid: 12 chunks x 64 q-blocks = 768 = 3 x 256CU exact; 256 threads.
// K LDS linear [32][256] w/ XOR-swizzled SOURCE (slot^=(row&7)) -> 2-way reads.
// V LDS linear [256][32] = contiguous copy of VTb tile; PV reads contiguous.
// No staging registers -> ~154 unified regs -> 3 blocks/CU (12 waves).
__global__ __launch_bounds__(256, 3) void flash_kernel(
    const half_t* __restrict__ Qe, const half_t* __restrict__ Ke, const half_t* __restrict__ VTb,
    half_t* __restrict__ AOp, float* __restrict__ Lse)
{
    __shared__ __align__(16) half_t Ks[32 * 256];   // 16 KB, swizzled content
    __shared__ __align__(16) half_t Vs[256 * 32];   // 16 KB, linear tile
    __shared__ __align__(16) half_t Ps[4][16 * 40]; // per-wave P, 5 KB

    int b = blockIdx.x;
    int qb = b & 63;
    int chunk = b >> 6;          // consecutive 64 blocks share a chunk (L2)
    int tid = threadIdx.x;
    int w = tid >> 6, l = tid & 63;
    int l16 = l & 15, l4 = l >> 4;
    long qw0 = (long)qb * 64 + w * 16;

    int t0 = (NTILES * chunk) / NSPLIT;
    int t1 = (NTILES * (chunk + 1)) / NSPLIT;

    f16x8 qf[8];    // Q (pre-scaled by SCQ) as B-operand
#pragma unroll
    for (int ks = 0; ks < 8; ++ks)
        qf[ks] = *reinterpret_cast<const f16x8*>(Qe + (qw0 + l16) * 256 + ks * 32 + l4 * 8);

    f32x4 o[16];
#pragma unroll
    for (int i = 0; i < 16; ++i) o[i] = (f32x4){0.f, 0.f, 0.f, 0.f};
    float mrun = -3.0e38f;
    float lsum = 0.0f;

    // DMA stage of tile t: wave w fills LDS bytes [w*4K, (w+1)*4K) of each buf
#define STAGE(t) do {                                                        \
        const half_t* kb_ = Ke + (long)(t) * 32 * 256;                       \
        const half_t* vb_ = VTb + (long)(t) * 8192;                          \
        _Pragma("unroll")                                                    \
        for (int j = 0; j < 4; ++j) {                                        \
            int pb = w * 4096 + j * 1024;                                    \
            int p  = pb + l * 16;                                            \
            int row = p >> 9;                                                \
            int cols = ((p >> 4) & 31) ^ (row & 7);                          \
            GLD16(kb_ + row * 256 + cols * 8, Ks + (pb >> 1));               \
            GLD16(vb_ + (p >> 1), Vs + (pb >> 1));                           \
        }                                                                    \
    } while (0)

    STAGE(t0);
    __syncthreads();            // compiler drains vmcnt(0) before barrier

    half_t* Pw = Ps[w];
    const int xk = l16 & 7;

    for (int t = t0; t < t1; ++t) {
        // swapped QK^T: S^T[kv][q]; lane: col=q=l16, row=kv
        f32x4 s0 = (f32x4){0.f, 0.f, 0.f, 0.f};
        f32x4 s1 = (f32x4){0.f, 0.f, 0.f, 0.f};
#pragma unroll
        for (int ks = 0; ks < 8; ++ks) {
            int slot = ((ks * 4 + l4) ^ xk) << 3;
            f16x8 ka0 = *reinterpret_cast<const f16x8*>(Ks + l16 * 256 + slot);
            f16x8 ka1 = *reinterpret_cast<const f16x8*>(Ks + (16 + l16) * 256 + slot);
            s0 = __builtin_amdgcn_mfma_f32_16x16x32_f16(ka0, qf[ks], s0, 0, 0, 0);
            s1 = __builtin_amdgcn_mfma_f32_16x16x32_f16(ka1, qf[ks], s1, 0, 0, 0);
        }

        float tv[8];
#pragma unroll
        for (int r = 0; r < 4; ++r) { tv[r] = s0[r]; tv[4 + r] = s1[r]; }
        float pm = tv[0];
#pragma unroll
        for (int i = 1; i < 8; ++i) pm = fmaxf(pm, tv[i]);
        pm = fmaxf(pm, __shfl_xor(pm, 16));
        pm = fmaxf(pm, __shfl_xor(pm, 32));

        if (!__all(pm - mrun <= 8.0f)) {    // defer-max rescale
            float mn = fmaxf(mrun, pm);
            float alpha = __builtin_amdgcn_exp2f(mrun - mn);
            lsum *= alpha;
            float ao[4];
#pragma unroll
            for (int r = 0; r < 4; ++r) ao[r] = __shfl(alpha, l4 * 4 + r);
#pragma unroll
            for (int i = 0; i < 16; ++i)
#pragma unroll
                for (int r = 0; r < 4; ++r) o[i][r] *= ao[r];
            mrun = mn;
        }

        float p[8];
        float psum = 0.f;
#pragma unroll
        for (int i = 0; i < 8; ++i) { p[i] = __builtin_amdgcn_exp2f(tv[i] - mrun); psum += p[i]; }
        psum += __shfl_xor(psum, 16);
        psum += __shfl_xor(psum, 32);
        lsum += psum;

        f16x4 pk0, pk1;
#pragma unroll
        for (int r = 0; r < 4; ++r) { pk0[r] = (half_t)p[r]; pk1[r] = (half_t)p[4 + r]; }
        *reinterpret_cast<f16x4*>(Pw + l16 * 40 + l4 * 4) = pk0;
        *reinterpret_cast<f16x4*>(Pw + l16 * 40 + 16 + l4 * 4) = pk1;

        // PV: A = P[q][kv32] (one b128), B = V[kv][d] from Vs (contiguous)
        f16x8 pa = *reinterpret_cast<const f16x8*>(Pw + l16 * 40 + l4 * 8);
#pragma unroll
        for (int nt = 0; nt < 16; ++nt) {
            f16x8 vbf = *reinterpret_cast<const f16x8*>(Vs + (nt * 16 + l16) * 32 + l4 * 8);
            o[nt] = __builtin_amdgcn_mfma_f32_16x16x32_f16(pa, vbf, o[nt], 0, 0, 0);
        }

        if (t + 1 < t1) {
            __syncthreads();        // all waves done reading tile t
            STAGE(t + 1);           // DMA next tile
            __syncthreads();        // drains vmcnt(0) -> tile t+1 visible
        }
    }
#undef STAGE

    // epilogue: normalized f16 partials + LSE (v_log_f32 = log2)
    float inv[4];
#pragma unroll
    for (int r = 0; r < 4; ++r) inv[r] = 1.0f / __shfl(lsum, l4 * 4 + r);
    half_t* Ab = AOp + ((long)chunk * SQN + qw0) * 256;
#pragma unroll
    for (int nt = 0; nt < 16; ++nt)
#pragma unroll
        for (int r = 0; r < 4; ++r)
            Ab[(l4 * 4 + r) * 256 + nt * 16 + l16] = (half_t)(o[nt][r] * inv[r]);
    if (l < 16)
        Lse[(long)chunk * SQN + qw0 + l16] = mrun + __builtin_amdgcn_logf(lsum);
}

// ---------------- combine KV-split partials -> AO (f16) ----------------------
__global__ __launch_bounds__(256) void reduce_kernel(
    const half_t* __restrict__ AOp, const float* __restrict__ Lse, half_t* __restrict__ AO)
{
    int tid = threadIdx.x;
    long q = (long)blockIdx.x * 4 + (tid >> 6);
    int d0 = (tid & 63) * 4;
    float ls[NSPLIT];
    float lmax = -3.0e38f;
#pragma unroll
    for (int i = 0; i < NSPLIT; ++i) { ls[i] = Lse[(long)i * SQN + q]; lmax = fmaxf(lmax, ls[i]); }
    f32x4 acc = (f32x4){0.f, 0.f, 0.f, 0.f};
    float wsum = 0.f;
#pragma unroll
    for (int i = 0; i < NSPLIT; ++i) {
        float wgt = __builtin_amdgcn_exp2f(ls[i] - lmax);
        wsum += wgt;
        f16x4 ov = *reinterpret_cast<const f16x4*>(AOp + ((long)i * SQN + q) * 256 + d0);
#pragma unroll
        for (int r = 0; r < 4; ++r) acc[r] += wgt * (float)ov[r];
    }
    float inv = 1.0f / wsum;
    f16x4 pk;
#pragma unroll
    for (int r = 0; r < 4; ++r) pk[r] = (half_t)(acc[r] * inv);
    *reinterpret_cast<f16x4*>(AO + q * 256 + d0) = pk;
}

// ---------------- O projection ----------------------------------------------
__global__ __launch_bounds__(256) void oproj_kernel(
    const half_t* __restrict__ AO, const half_t* __restrict__ WTo,
    const float* __restrict__ ob, float* __restrict__ out)
{
    int b = blockIdx.x;
    int tid = threadIdx.x;
    int w = tid >> 6, l = tid & 63;
    int l16 = l & 15, l4 = l >> 4;
    long r0 = (long)b * 64 + w * 16;
    f32x4 acc[16];
#pragma unroll
    for (int i = 0; i < 16; ++i) acc[i] = (f32x4){0.f, 0.f, 0.f, 0.f};
#pragma unroll
    for (int ks = 0; ks < 8; ++ks) {
        f16x8 af = *reinterpret_cast<const f16x8*>(AO + (r0 + l16) * 256 + ks * 32 + l4 * 8);
#pragma unroll
        for (int nt = 0; nt < 16; ++nt) {
            f16x8 bf = *reinterpret_cast<const f16x8*>(WTo + (nt * 16 + l16) * 256 + ks * 32 + l4 * 8);
            acc[nt] = __builtin_amdgcn_mfma_f32_16x16x32_f16(af, bf, acc[nt], 0, 0, 0);
        }
    }
#pragma unroll
    for (int nt = 0; nt < 16; ++nt) {
        int d = nt * 16 + l16;
        float bv = ob[d];
#pragma unroll
        for (int r = 0; r < 4; ++r)
            out[(r0 + l4 * 4 + r) * 256 + d] = acc[nt][r] + bv;
    }
}

extern "C" void kernel_launch(void* const* d_in, const int* in_sizes, int n_in,
                              void* d_out, int out_size, void* d_ws, size_t ws_size,
                              hipStream_t stream) {
    const float* query = (const float*)d_in[0];
    const float* key   = (const float*)d_in[1];
    const float* value = (const float*)d_in[2];
    const float* cosp  = (const float*)d_in[3];
    const float* sinp  = (const float*)d_in[4];
    const float* qw = (const float*)d_in[5];
    const float* qb = (const float*)d_in[6];
    const float* kw = (const float*)d_in[7];
    const float* kb = (const float*)d_in[8];
    const float* vw = (const float*)d_in[9];
    const float* vb = (const float*)d_in[10];
    const float* ow = (const float*)d_in[11];
    const float* ob = (const float*)d_in[12];

    char* ws = (char*)d_ws;
    half_t* Qe  = (half_t*)(ws);                     // 4096*256*2       = 2,097,152
    half_t* Ke  = (half_t*)(ws + 2097152);           // 16448*256*2      = 8,421,376
    half_t* VTb = (half_t*)(ws + 10518528);          // 514*256*32*2     = 8,421,376
    half_t* WT  = (half_t*)(ws + 18939904);          // 4*256*256*2      = 524,288
    half_t* AOp = (half_t*)(ws + 19464192);          // 12*4096*256*2    = 25,165,824
    float*  Lse = (float*)(ws + 44630016);           // 12*4096*4        = 196,608
    half_t* AO  = (half_t*)(ws + 44826624);          // 4096*256*2       = 2,097,152
    // total ws use: 46,923,776 bytes

    hipLaunchKernelGGL(wt_kernel, dim3(64), dim3(256), 0, stream, qw, kw, vw, ow, WT);
    hipLaunchKernelGGL(proj_kernel, dim3(578), dim3(256), 0, stream,
                       query, key, value, cosp, sinp, WT, qb, kb, vb, Qe, Ke, VTb);
    hipLaunchKernelGGL(flash_kernel, dim3(64 * NSPLIT), dim3(256), 0, stream, Qe, Ke, VTb, AOp, Lse);
    hipLaunchKernelGGL(reduce_kernel, dim3(1024), dim3(256), 0, stream, AOp, Lse, AO);
    hipLaunchKernelGGL(oproj_kernel, dim3(64), dim3(256), 0, stream, AO, WT + 3 * 65536, ob, (float*)d_out);
}

// Round 6
// 188.382 us; speedup vs baseline: 1.5916x; 1.0899x over previous
//
#include <hip/hip_runtime.h>
#include <stdint.h>

typedef _Float16 half_t;
typedef __attribute__((ext_vector_type(8))) _Float16 f16x8;
typedef __attribute__((ext_vector_type(4))) _Float16 f16x4;
typedef __attribute__((ext_vector_type(4))) float f32x4;

#define SQN 4096
#define SKN 16448
#define NROPE 16384
#define NSPLIT 8
#define NTILES 514          // 16448 / 32
#define SCQ 0.090168441360f // log2(e) / 16  (folded into Q at proj time)

// async global->LDS, 16B per lane; LDS dest = wave-uniform base + lane*16
#define GLD16(gp, lp) __builtin_amdgcn_global_load_lds( \
    (const __attribute__((address_space(1))) void*)(const void*)(gp), \
    (__attribute__((address_space(3))) void*)(void*)(lp), 16, 0, 0)

// ---------------- weight transpose: W[k][n] f32 -> WT[n][k] f16 (4 mats) ------
__global__ __launch_bounds__(256) void wt_kernel(const float* __restrict__ qw,
    const float* __restrict__ kw, const float* __restrict__ vw, const float* __restrict__ ow,
    half_t* __restrict__ wt)
{
    __shared__ float tile[64][65];
    int b = blockIdx.x;
    int mat = b >> 4, t4 = b & 15;
    int k0 = (t4 >> 2) << 6, n0 = (t4 & 3) << 6;
    const float* W = (mat == 0) ? qw : (mat == 1) ? kw : (mat == 2) ? vw : ow;
    half_t* WT = wt + mat * 65536;
    int t = threadIdx.x;
#pragma unroll
    for (int j = 0; j < 16; ++j) {
        int e = j * 256 + t;
        tile[e >> 6][e & 63] = W[(k0 + (e >> 6)) * 256 + n0 + (e & 63)];
    }
    __syncthreads();
#pragma unroll
    for (int j = 0; j < 16; ++j) {
        int e = j * 256 + t;
        WT[(n0 + (e >> 6)) * 256 + k0 + (e & 63)] = (half_t)tile[e & 63][e >> 6];
    }
}

// ---------------- fused QKV projection + bias + RoPE -------------------------
// grid: 64 (Q) + 257 (K) + 257 (V) = 578 blocks, 256 threads (4 waves x 16 rows)
__global__ __launch_bounds__(256) void proj_kernel(
    const float* __restrict__ query, const float* __restrict__ key, const float* __restrict__ value,
    const float* __restrict__ cosp, const float* __restrict__ sinp,
    const half_t* __restrict__ wt,
    const float* __restrict__ qb, const float* __restrict__ kb, const float* __restrict__ vb,
    half_t* __restrict__ Qe, half_t* __restrict__ Ke, half_t* __restrict__ VTb)
{
    __shared__ __align__(16) half_t S[64 * 264];    // [row][d pad 264] for Q/K path

    int b = blockIdx.x;
    int mode; long row0;
    const float* X; const half_t* W; const float* bias;
    if (b < 64)       { mode = 0; row0 = (long)b * 64;         X = query; W = wt;           bias = qb; }
    else if (b < 321) { mode = 1; row0 = (long)(b - 64) * 64;  X = key;   W = wt + 65536;   bias = kb; }
    else              { mode = 2; row0 = (long)(b - 321) * 64; X = value; W = wt + 131072;  bias = vb; }

    int tid = threadIdx.x;
    int w = tid >> 6, l = tid & 63;
    int l16 = l & 15, l4 = l >> 4;
    long rw0 = row0 + w * 16;

    f32x4 acc[16];
#pragma unroll
    for (int i = 0; i < 16; ++i) acc[i] = (f32x4){0.f, 0.f, 0.f, 0.f};

    const float* xrow = X + (rw0 + l16) * 256;
    for (int ks = 0; ks < 8; ++ks) {
        f32x4 xa = *reinterpret_cast<const f32x4*>(xrow + ks * 32 + l4 * 8);
        f32x4 xb = *reinterpret_cast<const f32x4*>(xrow + ks * 32 + l4 * 8 + 4);
        f16x8 af;
#pragma unroll
        for (int j = 0; j < 4; ++j) { af[j] = (half_t)xa[j]; af[4 + j] = (half_t)xb[j]; }
#pragma unroll
        for (int nt = 0; nt < 16; ++nt) {
            f16x8 bf = *reinterpret_cast<const f16x8*>(W + (nt * 16 + l16) * 256 + ks * 32 + l4 * 8);
            acc[nt] = __builtin_amdgcn_mfma_f32_16x16x32_f16(af, bf, acc[nt], 0, 0, 0);
        }
    }

    bool dorope = (mode == 0) || (mode == 1 && row0 < NROPE);
#pragma unroll
    for (int nt = 0; nt < 16; ++nt) {
        int d = nt * 16 + l16;
        float bv = bias[d];
        f32x4 v = acc[nt];
#pragma unroll
        for (int r = 0; r < 4; ++r) v[r] += bv;
        if (dorope) {
#pragma unroll
            for (int r = 0; r < 4; ++r) {
                long m = rw0 + l4 * 4 + r;
                long crow = (mode == 0) ? m : (m >> 2);
                float c = cosp[crow * 256 + d];
                float s = sinp[crow * 256 + d];
                float val = v[r];
                float other = __shfl_xor(val, 1);
                float rot = (d & 1) ? other : -other;
                v[r] = val * c + rot * s;
                if (mode == 0) v[r] *= SCQ;     // fold softmax scale into Q
            }
        }
        if (mode == 2) {        // direct tiled store: VTb[kvb][d][kv&31]
            long kv = rw0 + l4 * 4;
            long kvb = kv >> 5;
            int  kvw = (int)(kv & 31);
            f16x4 pk;
#pragma unroll
            for (int r = 0; r < 4; ++r) pk[r] = (half_t)v[r];
            *reinterpret_cast<f16x4*>(VTb + kvb * 8192 + (long)d * 32 + kvw) = pk;
        } else {                // stage to LDS for coalesced row-major store
            int wrow = w * 16 + l4 * 4;
#pragma unroll
            for (int r = 0; r < 4; ++r)
                S[(wrow + r) * 264 + d] = (half_t)v[r];
        }
    }

    if (mode != 2) {
        __syncthreads();
        half_t* O = ((mode == 0) ? Qe : Ke) + row0 * 256;
#pragma unroll
        for (int i = 0; i < 8; ++i) {
            int e = (i * 256 + tid) * 8;        // 64 rows x 256 d, 16B chunks
            int row = e >> 8, col = e & 255;
            f16x8 val = *reinterpret_cast<const f16x8*>(&S[row * 264 + col]);
            *reinterpret_cast<f16x8*>(O + e) = val;
        }
    }
}

// ---------------- flash attention: double-buffered DMA pipeline --------------
// grid: 512 blocks (chunk = b&7 -> XCD-pinned; qb = b>>3), 256 threads.
// T3 2-phase: STAGE(next) issued BEFORE compute; one vmcnt(0)+s_barrier per
// tile at the END (compute covers DMA latency). LDS 70.7KB -> 2 blocks/CU.
__global__ __launch_bounds__(256, 2) void flash_kernel(
    const half_t* __restrict__ Qe, const half_t* __restrict__ Ke, const half_t* __restrict__ VTb,
    half_t* __restrict__ AOp, float* __restrict__ Lse)
{
    __shared__ __align__(16) half_t Ks[2][32 * 256];   // 2 x 16 KB, swizzled content
    __shared__ __align__(16) half_t Vs[2][256 * 32];   // 2 x 16 KB, linear tile
    __shared__ __align__(16) half_t Ps[4][16 * 40];    // per-wave P, 5 KB

    int b = blockIdx.x;
    int chunk = b & 7;           // == XCD id under round-robin dispatch: L2-pinned K/V slice
    int qb = b >> 3;
    int tid = threadIdx.x;
    int w = tid >> 6, l = tid & 63;
    int l16 = l & 15, l4 = l >> 4;
    long qw0 = (long)qb * 64 + w * 16;

    int t0 = (NTILES * chunk) / NSPLIT;
    int t1 = (NTILES * (chunk + 1)) / NSPLIT;

    f16x8 qf[8];    // Q (pre-scaled by SCQ) as B-operand
#pragma unroll
    for (int ks = 0; ks < 8; ++ks)
        qf[ks] = *reinterpret_cast<const f16x8*>(Qe + (qw0 + l16) * 256 + ks * 32 + l4 * 8);

    f32x4 o[16];
#pragma unroll
    for (int i = 0; i < 16; ++i) o[i] = (f32x4){0.f, 0.f, 0.f, 0.f};
    float mrun = -3.0e38f;
    float lsum = 0.0f;

    // DMA stage of tile t into buffer d_: wave w fills bytes [w*4K,(w+1)*4K)
#define STAGE(d_, t) do {                                                    \
        const half_t* kb_ = Ke + (long)(t) * 8192;                           \
        const half_t* vb_ = VTb + (long)(t) * 8192;                          \
        half_t* ksd = &Ks[d_][0];                                            \
        half_t* vsd = &Vs[d_][0];                                            \
        _Pragma("unroll")                                                    \
        for (int j = 0; j < 4; ++j) {                                        \
            int pb = w * 4096 + j * 1024;                                    \
            int p  = pb + l * 16;                                            \
            int row = p >> 9;                                                \
            int cols = ((p >> 4) & 31) ^ (row & 7);                          \
            GLD16(kb_ + row * 256 + cols * 8, ksd + (pb >> 1));              \
            GLD16(vb_ + (p >> 1), vsd + (pb >> 1));                          \
        }                                                                    \
    } while (0)

    STAGE(0, t0);
    asm volatile("s_waitcnt vmcnt(0)" ::: "memory");
    __builtin_amdgcn_s_barrier();

    half_t* Pw = Ps[w];
    const int xk = l16 & 7;
    int cur = 0;

    for (int t = t0; t < t1; ++t) {
        if (t + 1 < t1) STAGE(cur ^ 1, t + 1);   // issue next-tile DMA FIRST

        const half_t* KsC = &Ks[0][0] + cur * (32 * 256);
        const half_t* VsC = &Vs[0][0] + cur * (256 * 32);

        // swapped QK^T: S^T[kv][q]; lane: col=q=l16, row=kv
        f32x4 s0 = (f32x4){0.f, 0.f, 0.f, 0.f};
        f32x4 s1 = (f32x4){0.f, 0.f, 0.f, 0.f};
#pragma unroll
        for (int ks = 0; ks < 8; ++ks) {
            int slot = ((ks * 4 + l4) ^ xk) << 3;
            f16x8 ka0 = *reinterpret_cast<const f16x8*>(KsC + l16 * 256 + slot);
            f16x8 ka1 = *reinterpret_cast<const f16x8*>(KsC + (16 + l16) * 256 + slot);
            s0 = __builtin_amdgcn_mfma_f32_16x16x32_f16(ka0, qf[ks], s0, 0, 0, 0);
            s1 = __builtin_amdgcn_mfma_f32_16x16x32_f16(ka1, qf[ks], s1, 0, 0, 0);
        }

        float tv[8];
#pragma unroll
        for (int r = 0; r < 4; ++r) { tv[r] = s0[r]; tv[4 + r] = s1[r]; }
        float pm = tv[0];
#pragma unroll
        for (int i = 1; i < 8; ++i) pm = fmaxf(pm, tv[i]);
        pm = fmaxf(pm, __shfl_xor(pm, 16));
        pm = fmaxf(pm, __shfl_xor(pm, 32));

        if (!__all(pm - mrun <= 8.0f)) {    // defer-max rescale
            float mn = fmaxf(mrun, pm);
            float alpha = __builtin_amdgcn_exp2f(mrun - mn);
            lsum *= alpha;
            float ao[4];
#pragma unroll
            for (int r = 0; r < 4; ++r) ao[r] = __shfl(alpha, l4 * 4 + r);
#pragma unroll
            for (int i = 0; i < 16; ++i)
#pragma unroll
                for (int r = 0; r < 4; ++r) o[i][r] *= ao[r];
            mrun = mn;
        }

        float p[8];
        float psum = 0.f;
#pragma unroll
        for (int i = 0; i < 8; ++i) { p[i] = __builtin_amdgcn_exp2f(tv[i] - mrun); psum += p[i]; }
        psum += __shfl_xor(psum, 16);
        psum += __shfl_xor(psum, 32);
        lsum += psum;

        f16x4 pk0, pk1;
#pragma unroll
        for (int r = 0; r < 4; ++r) { pk0[r] = (half_t)p[r]; pk1[r] = (half_t)p[4 + r]; }
        *reinterpret_cast<f16x4*>(Pw + l16 * 40 + l4 * 4) = pk0;
        *reinterpret_cast<f16x4*>(Pw + l16 * 40 + 16 + l4 * 4) = pk1;

        // PV: A = P[q][kv32] (one b128), B = V[kv][d] from Vs (contiguous)
        f16x8 pa = *reinterpret_cast<const f16x8*>(Pw + l16 * 40 + l4 * 8);
#pragma unroll
        for (int nt = 0; nt < 16; ++nt) {
            f16x8 vbf = *reinterpret_cast<const f16x8*>(VsC + (nt * 16 + l16) * 32 + l4 * 8);
            o[nt] = __builtin_amdgcn_mfma_f32_16x16x32_f16(pa, vbf, o[nt], 0, 0, 0);
        }

        // single drain+barrier per tile: (a) my next-tile DMA landed; barrier ->
        // everyone's landed AND everyone done reading buf[cur] before overwrite
        asm volatile("s_waitcnt vmcnt(0)" ::: "memory");
        __builtin_amdgcn_s_barrier();
        cur ^= 1;
    }
#undef STAGE

    // epilogue: normalized f16 partials + LSE (v_log_f32 = log2)
    float inv[4];
#pragma unroll
    for (int r = 0; r < 4; ++r) inv[r] = 1.0f / __shfl(lsum, l4 * 4 + r);
    half_t* Ab = AOp + ((long)chunk * SQN + qw0) * 256;
#pragma unroll
    for (int nt = 0; nt < 16; ++nt)
#pragma unroll
        for (int r = 0; r < 4; ++r)
            Ab[(l4 * 4 + r) * 256 + nt * 16 + l16] = (half_t)(o[nt][r] * inv[r]);
    if (l < 16)
        Lse[(long)chunk * SQN + qw0 + l16] = mrun + __builtin_amdgcn_logf(lsum);
}

// ---------------- fused reduce + O projection --------------------------------
// grid: 256 blocks x 256 thr; block -> 16 rows, wave w -> cols w*64..+64.
// A-fragment = LSE-weighted sum of the 8 AOp chunks, built in registers.
__global__ __launch_bounds__(256) void oproj_kernel(
    const half_t* __restrict__ AOp, const float* __restrict__ Lse,
    const half_t* __restrict__ WTo, const float* __restrict__ ob,
    float* __restrict__ out)
{
    int b = blockIdx.x;
    int tid = threadIdx.x;
    int w = tid >> 6, l = tid & 63;
    int l16 = l & 15, l4 = l >> 4;
    long row = (long)b * 16 + l16;

    // per-row chunk weights
    float ls[NSPLIT];
    float lmax = -3.0e38f;
#pragma unroll
    for (int c = 0; c < NSPLIT; ++c) { ls[c] = Lse[(long)c * SQN + row]; lmax = fmaxf(lmax, ls[c]); }
    float wgt[NSPLIT];
    float wsum = 0.f;
#pragma unroll
    for (int c = 0; c < NSPLIT; ++c) { wgt[c] = __builtin_amdgcn_exp2f(ls[c] - lmax); wsum += wgt[c]; }
    float invw = 1.0f / wsum;
#pragma unroll
    for (int c = 0; c < NSPLIT; ++c) wgt[c] *= invw;

    f32x4 acc[4];
#pragma unroll
    for (int i = 0; i < 4; ++i) acc[i] = (f32x4){0.f, 0.f, 0.f, 0.f};

#pragma unroll
    for (int ks = 0; ks < 8; ++ks) {
        float facc[8];
#pragma unroll
        for (int j = 0; j < 8; ++j) facc[j] = 0.f;
#pragma unroll
        for (int c = 0; c < NSPLIT; ++c) {
            f16x8 v = *reinterpret_cast<const f16x8*>(
                AOp + ((long)c * SQN + row) * 256 + ks * 32 + l4 * 8);
#pragma unroll
            for (int j = 0; j < 8; ++j) facc[j] += wgt[c] * (float)v[j];
        }
        f16x8 af;
#pragma unroll
        for (int j = 0; j < 8; ++j) af[j] = (half_t)facc[j];
#pragma unroll
        for (int nt = 0; nt < 4; ++nt) {
            f16x8 bf = *reinterpret_cast<const f16x8*>(
                WTo + ((w * 4 + nt) * 16 + l16) * 256 + ks * 32 + l4 * 8);
            acc[nt] = __builtin_amdgcn_mfma_f32_16x16x32_f16(af, bf, acc[nt], 0, 0, 0);
        }
    }

    long r0 = (long)b * 16;
#pragma unroll
    for (int nt = 0; nt < 4; ++nt) {
        int d = (w * 4 + nt) * 16 + l16;
        float bv = ob[d];
#pragma unroll
        for (int r = 0; r < 4; ++r)
            out[(r0 + l4 * 4 + r) * 256 + d] = acc[nt][r] + bv;
    }
}

extern "C" void kernel_launch(void* const* d_in, const int* in_sizes, int n_in,
                              void* d_out, int out_size, void* d_ws, size_t ws_size,
                              hipStream_t stream) {
    const float* query = (const float*)d_in[0];
    const float* key   = (const float*)d_in[1];
    const float* value = (const float*)d_in[2];
    const float* cosp  = (const float*)d_in[3];
    const float* sinp  = (const float*)d_in[4];
    const float* qw = (const float*)d_in[5];
    const float* qb = (const float*)d_in[6];
    const float* kw = (const float*)d_in[7];
    const float* kb = (const float*)d_in[8];
    const float* vw = (const float*)d_in[9];
    const float* vb = (const float*)d_in[10];
    const float* ow = (const float*)d_in[11];
    const float* ob = (const float*)d_in[12];

    char* ws = (char*)d_ws;
    half_t* Qe  = (half_t*)(ws);                     // 4096*256*2       = 2,097,152
    half_t* Ke  = (half_t*)(ws + 2097152);           // 16448*256*2      = 8,421,376
    half_t* VTb = (half_t*)(ws + 10518528);          // 514*256*32*2     = 8,421,376
    half_t* WT  = (half_t*)(ws + 18939904);          // 4*256*256*2      = 524,288
    half_t* AOp = (half_t*)(ws + 19464192);          // 8*4096*256*2     = 16,777,216
    float*  Lse = (float*)(ws + 36241408);           // 8*4096*4         = 131,072
    // total ws use: 36,372,480 bytes (< 46,923,776 proven)

    hipLaunchKernelGGL(wt_kernel, dim3(64), dim3(256), 0, stream, qw, kw, vw, ow, WT);
    hipLaunchKernelGGL(proj_kernel, dim3(578), dim3(256), 0, stream,
                       query, key, value, cosp, sinp, WT, qb, kb, vb, Qe, Ke, VTb);
    hipLaunchKernelGGL(flash_kernel, dim3(512), dim3(256), 0, stream, Qe, Ke, VTb, AOp, Lse);
    hipLaunchKernelGGL(oproj_kernel, dim3(256), dim3(256), 0, stream, AOp, Lse, WT + 3 * 65536, ob, (float*)d_out);
}